// Round 12
// baseline (250.058 us; speedup 1.0000x reference)
//
#include <hip/hip_runtime.h>
#include <math.h>

#define K_EMB 512
#define DIM 64
#define NVEC 65536                      // 64*32*32
#define OUT_LOSS 0
#define OUT_Q 1
#define OUT_PERP (1 + NVEC * DIM)       // 4194305
#define OUT_IDX (1 + NVEC * DIM + 1)    // 4194306
#define EPS2 1e-4f                      // ambiguity margin (fast-path err bound ~2e-5)
#define FIX_CAP 16                      // per 32-vec block
#define GRID_MAIN 2048
#define SSE_SLOTS 32

typedef __attribute__((ext_vector_type(8))) short short8;   // 8 bf16 (4 VGPRs)
typedef __attribute__((ext_vector_type(4))) float float4v;  // MFMA acc

// ws layout (bytes):
// [0,2048)        csq[512] fp32 (numpy-order, used by exact replay)
// [2048,2304)     double sse64[32]
// [2304,2308)     u32 done-counter
// [2560,4608)     u32 hist[512]
// [4608,70144)    ahi: codebook hi-bf16 A-fragments [t=32][step=2][lane=64][8]
// [70144,135680)  alo: codebook lo-bf16 A-fragments
// [135680,168448) csqf: per-(t,lane) float4 of (-csq/2) for MFMA acc-init fold

__device__ __forceinline__ unsigned short bf16_rn(float f) {
    unsigned u = __float_as_uint(f);
    return (unsigned short)((u + 0x7FFFu + ((u >> 16) & 1u)) >> 16);
}

// numpy pairwise_sum replica for sum(v*v) over 64 elems (products rounded
// before summing, 8 stride-8 chains, pairwise combine) — matches np.sum.
__device__ __forceinline__ float np_pairwise8_sq(const float* v) {
    float r[8];
#pragma unroll
    for (int j = 0; j < 8; ++j) r[j] = __fmul_rn(v[j], v[j]);
#pragma unroll
    for (int i = 8; i < 64; i += 8) {
#pragma unroll
        for (int j = 0; j < 8; ++j) r[j] = __fadd_rn(r[j], __fmul_rn(v[i + j], v[i + j]));
    }
    return __fadd_rn(__fadd_rn(__fadd_rn(r[0], r[1]), __fadd_rn(r[2], r[3])),
                     __fadd_rn(__fadd_rn(r[4], r[5]), __fadd_rn(r[6], r[7])));
}

// identical arithmetic order, vectorized (b128) loads — for global csq pass
__device__ __forceinline__ float np_pairwise8_sq_g(const float* g) {
    float x[64];
    const float4* v4 = (const float4*)g;
#pragma unroll
    for (int i = 0; i < 16; ++i) {
        float4 t = v4[i];
        x[4 * i + 0] = t.x; x[4 * i + 1] = t.y; x[4 * i + 2] = t.z; x[4 * i + 3] = t.w;
    }
    float r[8];
#pragma unroll
    for (int j = 0; j < 8; ++j) r[j] = __fmul_rn(x[j], x[j]);
#pragma unroll
    for (int i = 8; i < 64; i += 8) {
#pragma unroll
        for (int j = 0; j < 8; ++j) r[j] = __fadd_rn(r[j], __fmul_rn(x[i + j], x[i + j]));
    }
    return __fadd_rn(__fadd_rn(__fadd_rn(r[0], r[1]), __fadd_rn(r[2], r[3])),
                     __fadd_rn(__fadd_rn(r[4], r[5]), __fadd_rn(r[6], r[7])));
}

// Prep: blocks 0..15 build A-fragments; blocks 16/17 split the csq/csqf work
// (R12: was one serial block — halves the slowest-prep-block wall time).
// Block 16: codewords [0,256) -> csq, hist zero, csqf tiles t<16, sse/cnt init.
// Block 17: codewords [256,512) -> csq, hist zero, csqf tiles t>=16.
__global__ void vq_frag(const float* __restrict__ codebook, float* __restrict__ csq,
                        unsigned short* __restrict__ ahi, unsigned short* __restrict__ alo,
                        float4* __restrict__ csqf, unsigned* __restrict__ hist,
                        double* __restrict__ sse64, unsigned* __restrict__ cnt) {
    const int tid = threadIdx.x;
    if (blockIdx.x < 16) {
        const int id = blockIdx.x * 256 + tid;           // 4096 conversions
        const int t = id >> 7, step = (id >> 6) & 1, lane = id & 63;
        const int m = t * 16 + (lane & 15);              // codebook row (A m-index)
        const int kb = step * 32 + (lane >> 4) * 8;      // A k-index base
        const float4* src = (const float4*)(codebook + (m << 6) + kb);
        float4 f0 = src[0], f1 = src[1];
        const float fs[8] = {f0.x, f0.y, f0.z, f0.w, f1.x, f1.y, f1.z, f1.w};
        short8 h, l;
#pragma unroll
        for (int j = 0; j < 8; ++j) {
            unsigned short hv = bf16_rn(fs[j]);
            float lof = fs[j] - __uint_as_float(((unsigned)hv) << 16);
            h[j] = (short)hv;
            l[j] = (short)bf16_rn(lof);
        }
        const int fo = ((t * 2 + step) * 64 + lane) * 8;
        *(short8*)(ahi + fo) = h;
        *(short8*)(alo + fo) = l;
    } else {
        __shared__ float s_csq[256];
        const int kbase = (blockIdx.x == 16) ? 0 : 256;  // this block's codeword half
        {
            const int k = kbase + tid;                   // 1 row/thread
            float v = np_pairwise8_sq_g(codebook + ((size_t)k << 6));
            s_csq[tid] = v;
            csq[k] = v;
            hist[k] = 0u;
        }
        if (blockIdx.x == 16) {
            if (tid < SSE_SLOTS) sse64[tid] = 0.0;
            if (tid == SSE_SLOTS) *cnt = 0u;
        }
        __syncthreads();
        // csqf entries for this half: tiles t in [kbase/16, kbase/16+16),
        // ids [kbase*4, kbase*4+1024), 4 per thread.
#pragma unroll
        for (int i = 0; i < 4; ++i) {
            const int id = kbase * 4 + i * 256 + tid;
            const int t = id >> 6, lane = id & 63;
            const int k0 = (t * 16 + (lane >> 4) * 4) - kbase;   // local in s_csq
            // store -csq/2 (exact: *0.5 and negate are exact fp32 ops) so the
            // k-loop inits the MFMA accumulator with it directly:
            // acc_final = dot - csq/2  ->  d2 = fmaf(-2, acc, A) = A - 2dot + csq
            csqf[id] = make_float4(-0.5f * s_csq[k0],     -0.5f * s_csq[k0 + 1],
                                   -0.5f * s_csq[k0 + 2], -0.5f * s_csq[k0 + 3]);
        }
    }
}

// Main: R9 proven structure restored EXACTLY (70.3us measured): 32 vecs/block,
// 4 waves, wave w owns k-tiles [8w,8w+8) in order, per-wave in-register
// conversion (R10/R11 proved the LDS-shared variant adds ~8us of critical-path
// lgkm latency — redundant in-register work is free on this latency-floored
// kernel, LDS round-trips are not), serial numpy A-phase, med3 float top-2,
// csq folded into MFMA acc-init. R12 deltas, both safe:
//  - __launch_bounds__(256,8): pins allocator to VGPR<=64 (the 8-blocks/CU
//    boundary R9 sits on; 65+ would halve occupancy at the 64/128 HW step).
//  - A2 hoist: the 16 loop-invariant s_A reads hoisted to 2 (guarded by the
//    VGPR bound; worst case the allocator rematerializes = R9 exactly).
__launch_bounds__(256, 8)
__global__ void vq_main(const float* __restrict__ inputs, const float* __restrict__ codebook,
                        const float* __restrict__ csq, const unsigned short* __restrict__ ahi,
                        const unsigned short* __restrict__ alo, const float4* __restrict__ csqf,
                        unsigned* __restrict__ hist, double* __restrict__ sse64,
                        unsigned* __restrict__ cnt, float* __restrict__ out) {
    __shared__ __align__(16) float s_x[32 * 68];     // 8.7 KB, stride 68
    __shared__ float s_A[32];
    __shared__ float s_m1[4][32];                    // per-wave top1/top2 (float)
    __shared__ float s_m2[4][32];
    __shared__ unsigned s_k1[4][32];                 // per-wave argmin index
    __shared__ unsigned s_idx[32];                   // final per-vec index
    __shared__ int s_fix[FIX_CAP];
    __shared__ int s_nfix;
    __shared__ float s_w[4];
    __shared__ int s_last;
    __shared__ float s_wsm[8];
    __shared__ double s_sse[SSE_SLOTS];

    const int tid = threadIdx.x;
    const int wave = tid >> 6, lane = tid & 63;
    const int vbase = blockIdx.x * 32;

    if (tid == 0) s_nfix = 0;

    // stage x (coalesced b128): 512 float4, 2 per thread
    {
        const float4* src = (const float4*)(inputs + ((size_t)vbase << 6));
#pragma unroll
        for (int i = 0; i < 2; ++i) {
            const int f = i * 256 + tid;
            float4 v = src[f];
            *(float4*)&s_x[(f >> 4) * 68 + (f & 15) * 4] = v;
        }
    }
    __syncthreads();

    // exact numpy-order ||x||^2 per vec (proven serial phase)
    if (tid < 32) s_A[tid] = np_pairwise8_sq(&s_x[tid * 68]);
    __syncthreads();

    // B-fragments (x) for all 32 vecs: per-wave, in-register (R9-proven):
    // 2 vec-tiles x 2 k-steps, hi+lo = 32 VGPRs
    short8 bhi[2][2], blo[2][2];
#pragma unroll
    for (int vt = 0; vt < 2; ++vt) {
        const int vrow = vt * 16 + (lane & 15);
#pragma unroll
        for (int step = 0; step < 2; ++step) {
            const int kb = step * 32 + (lane >> 4) * 8;
            float4 f0 = *(const float4*)&s_x[vrow * 68 + kb];
            float4 f1 = *(const float4*)&s_x[vrow * 68 + kb + 4];
            const float fs[8] = {f0.x, f0.y, f0.z, f0.w, f1.x, f1.y, f1.z, f1.w};
            short8 h, l;
#pragma unroll
            for (int j = 0; j < 8; ++j) {
                unsigned short hv = bf16_rn(fs[j]);
                float lof = fs[j] - __uint_as_float(((unsigned)hv) << 16);
                h[j] = (short)hv;
                l[j] = (short)bf16_rn(lof);
            }
            bhi[vt][step] = h;
            blo[vt][step] = l;
        }
    }
    // hoist loop-invariant A reads (was 16 LDS reads inside the k-loop)
    float A2[2];
    A2[0] = s_A[lane & 15];
    A2[1] = s_A[16 + (lane & 15)];

    const float INF = __builtin_inff();
    float m1[2] = {INF, INF}, m2[2] = {INF, INF};
    unsigned k1[2] = {0u, 0u};

#pragma unroll 2
    for (int tt = 0; tt < 8; ++tt) {
        const int t = wave * 8 + tt;                 // this wave's k-tiles, in order
        const int fo0 = ((t * 2 + 0) * 64 + lane) * 8;
        const int fo1 = ((t * 2 + 1) * 64 + lane) * 8;
        short8 ah0 = *(const short8*)(ahi + fo0);
        short8 ah1 = *(const short8*)(ahi + fo1);
        short8 al0 = *(const short8*)(alo + fo0);
        short8 al1 = *(const short8*)(alo + fo1);
        float4 cs = csqf[t * 64 + lane];             // = -csq/2 for 4 codewords
#pragma unroll
        for (int vt = 0; vt < 2; ++vt) {
            float4v acc = {cs.x, cs.y, cs.z, cs.w};  // csq folded into acc init
            acc = __builtin_amdgcn_mfma_f32_16x16x32_bf16(ah0, bhi[vt][0], acc, 0, 0, 0);
            acc = __builtin_amdgcn_mfma_f32_16x16x32_bf16(ah1, bhi[vt][1], acc, 0, 0, 0);
            acc = __builtin_amdgcn_mfma_f32_16x16x32_bf16(ah0, blo[vt][0], acc, 0, 0, 0);
            acc = __builtin_amdgcn_mfma_f32_16x16x32_bf16(ah1, blo[vt][1], acc, 0, 0, 0);
            acc = __builtin_amdgcn_mfma_f32_16x16x32_bf16(al0, bhi[vt][0], acc, 0, 0, 0);
            acc = __builtin_amdgcn_mfma_f32_16x16x32_bf16(al1, bhi[vt][1], acc, 0, 0, 0);
            const float Avt = A2[vt];
#pragma unroll
            for (int r = 0; r < 4; ++r) {
                // D: col=lane&15 (=vec in tile), row=(lane>>4)*4+r (=codeword)
                float d2 = __builtin_fmaf(-2.0f, acc[r], Avt);
                const unsigned k = (unsigned)(t * 16 + (lane >> 4) * 4 + r);
                // float top-2: 5 VALU (cmp, cndmask, med3, min) vs u64's ~10
                bool lt = d2 < m1[vt];               // strict: first occurrence
                k1[vt] = lt ? k : k1[vt];
                m2[vt] = __builtin_amdgcn_fmed3f(d2, m1[vt], m2[vt]);
                m1[vt] = fminf(d2, m1[vt]);
            }
        }
    }

    // merge 4 lane-groups (disjoint k-subsets, same vec), tie-break on k
#pragma unroll
    for (int vt = 0; vt < 2; ++vt) {
#pragma unroll
        for (int off = 16; off <= 32; off <<= 1) {
            float om1 = __shfl_xor(m1[vt], off);
            float om2 = __shfl_xor(m2[vt], off);
            unsigned ok1 = __shfl_xor(k1[vt], off);
            float hi = fmaxf(m1[vt], om1);
            float lo2 = fminf(m2[vt], om2);
            bool take = (om1 < m1[vt]) || (om1 == m1[vt] && ok1 < k1[vt]);
            k1[vt] = take ? ok1 : k1[vt];
            m1[vt] = fminf(m1[vt], om1);
            m2[vt] = fminf(hi, lo2);                 // 2nd-smallest of the union
        }
        if (lane < 16) {
            s_m1[wave][vt * 16 + lane] = m1[vt];
            s_m2[wave][vt * 16 + lane] = m2[vt];
            s_k1[wave][vt * 16 + lane] = k1[vt];
        }
    }
    __syncthreads();

    // cross-wave tournament -> global top-2 per vec. Waves scan in ascending
    // k-range order; strict < keeps first occurrence; equal m1 across waves
    // collapses the gap to 0 -> replay decides exactly.
    if (tid < 32) {
        float E1 = INF, E2 = INF;
        unsigned K1 = 0u;
#pragma unroll
        for (int w = 0; w < 4; ++w) {
            float a1 = s_m1[w][tid], a2 = s_m2[w][tid];
            unsigned ak = s_k1[w][tid];
            if (a1 < E1) { E2 = fminf(E1, a2); E1 = a1; K1 = ak; }
            else         { E2 = fminf(E2, a1); }     // a2 >= a1 -> a1 suffices
        }
        s_idx[tid] = K1;
        if (__fsub_rn(E2, E1) <= EPS2) {             // ambiguous -> exact replay
            int pos = atomicAdd(&s_nfix, 1);
            if (pos < FIX_CAP) s_fix[pos] = tid;
        }
    }
    __syncthreads();

    // exact numpy-order replay for ambiguous vecs (one wave each; rare)
    {
        int nf = s_nfix; if (nf > FIX_CAP) nf = FIX_CAP;
        for (int f = wave; f < nf; f += 4) {
            const int vloc = s_fix[f];
            const float* xr = &s_x[vloc * 68];   // wave-uniform -> LDS broadcast
            const float A = s_A[vloc];
            unsigned long long best = ~0ULL;
#pragma unroll 1
            for (int r8 = 0; r8 < 8; ++r8) {
                const int k = lane * 8 + r8;
                const float* c = codebook + (k << 6);
                float p[8] = {0.f, 0.f, 0.f, 0.f, 0.f, 0.f, 0.f, 0.f};
#pragma unroll
                for (int ii = 0; ii < 64; ii += 8)
#pragma unroll
                    for (int j = 0; j < 8; ++j)
                        p[j] = __builtin_fmaf(xr[ii + j], c[ii + j], p[j]);
                float dot = __fadd_rn(__fadd_rn(__fadd_rn(p[0], p[1]), __fadd_rn(p[2], p[3])),
                                      __fadd_rn(__fadd_rn(p[4], p[5]), __fadd_rn(p[6], p[7])));
                float d2 = __fadd_rn(__fsub_rn(A, __fmul_rn(2.0f, dot)), csq[k]);
                unsigned long long e = ((unsigned long long)__float_as_uint(d2) << 32) | (unsigned)k;
                if (e < best) best = e;
            }
#pragma unroll
            for (int off = 32; off > 0; off >>= 1) {
                unsigned long long o = __shfl_down(best, off);
                if (o < best) best = o;
            }
            if (lane == 0) s_idx[vloc] = (unsigned)best;   // ties -> smallest k
        }
    }
    __syncthreads();

    // epilogue: indices + hist atomics (32/block, spread addresses)
    if (tid < 32) {
        const unsigned kf = s_idx[tid];
        out[OUT_IDX + vbase + tid] = (float)kf;
        atomicAdd(&hist[kf], 1u);
    }
    // quantized (coalesced b128) + sse
    {
        float4* dst = (float4*)(out + OUT_Q + ((size_t)vbase << 6));
        float es = 0.f;
#pragma unroll
        for (int i = 0; i < 2; ++i) {
            const int f = i * 256 + tid;
            const int row = f >> 4, col = (f & 15) * 4;
            const unsigned k = s_idx[row];
            float4 qv = *(const float4*)(codebook + ((size_t)k << 6) + col);
            dst[f] = qv;
            float4 xv = *(const float4*)&s_x[row * 68 + col];
            float d0 = qv.x - xv.x; es = __builtin_fmaf(d0, d0, es);
            float d1 = qv.y - xv.y; es = __builtin_fmaf(d1, d1, es);
            float d2 = qv.z - xv.z; es = __builtin_fmaf(d2, d2, es);
            float d3 = qv.w - xv.w; es = __builtin_fmaf(d3, d3, es);
        }
#pragma unroll
        for (int off = 32; off > 0; off >>= 1) es += __shfl_down(es, off);
        if (lane == 0) s_w[wave] = es;
    }
    __syncthreads();
    // Ticket (R2-proven tail): __syncthreads drained each wave's vmem;
    // wave-local s_waitcnt orders the sse atomic before the ticket.
    if (tid == 0) {
        atomicAdd(&sse64[blockIdx.x & (SSE_SLOTS - 1)],
                  (double)(((s_w[0] + s_w[1]) + (s_w[2] + s_w[3]))));
        asm volatile("s_waitcnt vmcnt(0)" ::: "memory");
        unsigned ticket = atomicAdd(cnt, 1u);
        s_last = (ticket == GRID_MAIN - 1) ? 1 : 0;
    }
    __syncthreads();

    // last-finishing block computes final stats (replaces vq_final launch).
    // hist/sse read via device-scope atomic-RMW. Summation order bit-identical
    // to the original vq_final: s_wsm[w]=k[64w,..), s_wsm[4+w]=k[256+64w,..).
    if (s_last) {
        float pr0 = (float)atomicAdd(&hist[tid], 0u) / 65536.0f;
        float v0 = __fmul_rn(pr0, logf(__fadd_rn(pr0, 1e-10f)));
        float pr1 = (float)atomicAdd(&hist[tid + 256], 0u) / 65536.0f;
        float v1 = __fmul_rn(pr1, logf(__fadd_rn(pr1, 1e-10f)));
#pragma unroll
        for (int off = 32; off > 0; off >>= 1) {
            v0 += __shfl_down(v0, off);
            v1 += __shfl_down(v1, off);
        }
        if (lane == 0) { s_wsm[wave] = v0; s_wsm[4 + wave] = v1; }
        if (tid < SSE_SLOTS) s_sse[tid] = atomicAdd(&sse64[tid], 0.0);
        __syncthreads();
        if (tid == 0) {
            float S = 0.f;
#pragma unroll
            for (int i = 0; i < 8; ++i) S += s_wsm[i];
            out[OUT_PERP] = expf(-S);
            double sv = 0.0;
            for (int i = 0; i < SSE_SLOTS; ++i) sv += s_sse[i];
            float m = (float)(sv / 4194304.0);            // exact /2^22
            out[OUT_LOSS] = __fadd_rn(m, __fmul_rn(0.25f, m));
        }
    }
}

extern "C" void kernel_launch(void* const* d_in, const int* in_sizes, int n_in,
                              void* d_out, int out_size, void* d_ws, size_t ws_size,
                              hipStream_t stream) {
    const float* inputs   = (const float*)d_in[0];
    const float* codebook = (const float*)d_in[1];
    float* out = (float*)d_out;
    float*          csq   = (float*)d_ws;
    double*         sse64 = (double*)((char*)d_ws + 2048);
    unsigned*       cnt   = (unsigned*)((char*)d_ws + 2304);
    unsigned*       hist  = (unsigned*)((char*)d_ws + 2560);
    unsigned short* ahi   = (unsigned short*)((char*)d_ws + 4608);
    unsigned short* alo   = (unsigned short*)((char*)d_ws + 70144);
    float4*         csqf  = (float4*)((char*)d_ws + 135680);

    vq_frag<<<18, 256, 0, stream>>>(codebook, csq, ahi, alo, csqf, hist, sse64, cnt);
    vq_main<<<GRID_MAIN, 256, 0, stream>>>(inputs, codebook, csq, ahi, alo, csqf, hist, sse64, cnt, out);
}

// Round 13
// 130.754 us; speedup vs baseline: 1.9124x; 1.9124x over previous
//
#include <hip/hip_runtime.h>
#include <math.h>

#define K_EMB 512
#define DIM 64
#define NVEC 65536                      // 64*32*32
#define OUT_LOSS 0
#define OUT_Q 1
#define OUT_PERP (1 + NVEC * DIM)       // 4194305
#define OUT_IDX (1 + NVEC * DIM + 1)    // 4194306
#define EPS2 1e-4f                      // ambiguity margin (fast-path err bound ~2e-5)
#define FIX_CAP 16                      // per 32-vec block
#define GRID_MAIN 2048
#define SSE_SLOTS 32

typedef __attribute__((ext_vector_type(8))) short short8;   // 8 bf16 (4 VGPRs)
typedef __attribute__((ext_vector_type(4))) float float4v;  // MFMA acc

// ws layout (bytes):
// [0,2048)        csq[512] fp32 (numpy-order, used by exact replay)
// [2048,2304)     double sse64[32]
// [2304,2308)     u32 done-counter
// [2560,4608)     u32 hist[512]
// [4608,70144)    ahi: codebook hi-bf16 A-fragments [t=32][step=2][lane=64][8]
// [70144,135680)  alo: codebook lo-bf16 A-fragments
// [135680,168448) csqf: per-(t,lane) float4 of (-csq/2) for MFMA acc-init fold

__device__ __forceinline__ unsigned short bf16_rn(float f) {
    unsigned u = __float_as_uint(f);
    return (unsigned short)((u + 0x7FFFu + ((u >> 16) & 1u)) >> 16);
}

// numpy pairwise_sum replica for sum(v*v) over 64 elems (products rounded
// before summing, 8 stride-8 chains, pairwise combine) — matches np.sum.
__device__ __forceinline__ float np_pairwise8_sq(const float* v) {
    float r[8];
#pragma unroll
    for (int j = 0; j < 8; ++j) r[j] = __fmul_rn(v[j], v[j]);
#pragma unroll
    for (int i = 8; i < 64; i += 8) {
#pragma unroll
        for (int j = 0; j < 8; ++j) r[j] = __fadd_rn(r[j], __fmul_rn(v[i + j], v[i + j]));
    }
    return __fadd_rn(__fadd_rn(__fadd_rn(r[0], r[1]), __fadd_rn(r[2], r[3])),
                     __fadd_rn(__fadd_rn(r[4], r[5]), __fadd_rn(r[6], r[7])));
}

// identical arithmetic order, vectorized (b128) loads — for global csq pass
__device__ __forceinline__ float np_pairwise8_sq_g(const float* g) {
    float x[64];
    const float4* v4 = (const float4*)g;
#pragma unroll
    for (int i = 0; i < 16; ++i) {
        float4 t = v4[i];
        x[4 * i + 0] = t.x; x[4 * i + 1] = t.y; x[4 * i + 2] = t.z; x[4 * i + 3] = t.w;
    }
    float r[8];
#pragma unroll
    for (int j = 0; j < 8; ++j) r[j] = __fmul_rn(x[j], x[j]);
#pragma unroll
    for (int i = 8; i < 64; i += 8) {
#pragma unroll
        for (int j = 0; j < 8; ++j) r[j] = __fadd_rn(r[j], __fmul_rn(x[i + j], x[i + j]));
    }
    return __fadd_rn(__fadd_rn(__fadd_rn(r[0], r[1]), __fadd_rn(r[2], r[3])),
                     __fadd_rn(__fadd_rn(r[4], r[5]), __fadd_rn(r[6], r[7])));
}

// Prep: blocks 0..15 build A-fragments; blocks 16/17 split the csq/csqf work.
// Block 16: codewords [0,256) -> csq, hist zero, csqf tiles t<16, sse/cnt init.
// Block 17: codewords [256,512) -> csq, hist zero, csqf tiles t>=16.
__global__ void vq_frag(const float* __restrict__ codebook, float* __restrict__ csq,
                        unsigned short* __restrict__ ahi, unsigned short* __restrict__ alo,
                        float4* __restrict__ csqf, unsigned* __restrict__ hist,
                        double* __restrict__ sse64, unsigned* __restrict__ cnt) {
    const int tid = threadIdx.x;
    if (blockIdx.x < 16) {
        const int id = blockIdx.x * 256 + tid;           // 4096 conversions
        const int t = id >> 7, step = (id >> 6) & 1, lane = id & 63;
        const int m = t * 16 + (lane & 15);              // codebook row (A m-index)
        const int kb = step * 32 + (lane >> 4) * 8;      // A k-index base
        const float4* src = (const float4*)(codebook + (m << 6) + kb);
        float4 f0 = src[0], f1 = src[1];
        const float fs[8] = {f0.x, f0.y, f0.z, f0.w, f1.x, f1.y, f1.z, f1.w};
        short8 h, l;
#pragma unroll
        for (int j = 0; j < 8; ++j) {
            unsigned short hv = bf16_rn(fs[j]);
            float lof = fs[j] - __uint_as_float(((unsigned)hv) << 16);
            h[j] = (short)hv;
            l[j] = (short)bf16_rn(lof);
        }
        const int fo = ((t * 2 + step) * 64 + lane) * 8;
        *(short8*)(ahi + fo) = h;
        *(short8*)(alo + fo) = l;
    } else {
        __shared__ float s_csq[256];
        const int kbase = (blockIdx.x == 16) ? 0 : 256;  // this block's codeword half
        {
            const int k = kbase + tid;                   // 1 row/thread
            float v = np_pairwise8_sq_g(codebook + ((size_t)k << 6));
            s_csq[tid] = v;
            csq[k] = v;
            hist[k] = 0u;
        }
        if (blockIdx.x == 16) {
            if (tid < SSE_SLOTS) sse64[tid] = 0.0;
            if (tid == SSE_SLOTS) *cnt = 0u;
        }
        __syncthreads();
        // csqf entries for this half: ids [kbase*4, kbase*4+1024), 4 per thread.
#pragma unroll
        for (int i = 0; i < 4; ++i) {
            const int id = kbase * 4 + i * 256 + tid;
            const int t = id >> 6, lane = id & 63;
            const int k0 = (t * 16 + (lane >> 4) * 4) - kbase;   // local in s_csq
            // store -csq/2 (exact: *0.5 and negate are exact fp32 ops) so the
            // k-loop inits the MFMA accumulator with it directly:
            // acc_final = dot - csq/2  ->  d2 = fmaf(-2, acc, A) = A - 2dot + csq
            csqf[id] = make_float4(-0.5f * s_csq[k0],     -0.5f * s_csq[k0 + 1],
                                   -0.5f * s_csq[k0 + 2], -0.5f * s_csq[k0 + 3]);
        }
    }
}

// Main: EXACT R9 restore (proven 70.3us vq_main / 133.0us total, VGPR=64,
// no spills). R12's __launch_bounds__(256,8) forced the allocator to 32 VGPRs
// -> 400MB/dispatch scratch spill -> 193us. Lesson: set launch_bounds only to
// the occupancy you NEED — (256,4) lets the allocator settle at 64 VGPR and
// hardware runs 8 blocks/CU anyway. In-loop s_A reads kept (the A2-hoist was
// part of the VGPR pressure). Structure: R2 shell (32 vecs/block, 4 waves,
// wave w owns k-tiles [8w,8w+8) in order, serial numpy A-phase, per-wave
// in-register conversion) + R9 VALU-thinning (med3 float top-2, csq acc-fold).
__launch_bounds__(256, 4)
__global__ void vq_main(const float* __restrict__ inputs, const float* __restrict__ codebook,
                        const float* __restrict__ csq, const unsigned short* __restrict__ ahi,
                        const unsigned short* __restrict__ alo, const float4* __restrict__ csqf,
                        unsigned* __restrict__ hist, double* __restrict__ sse64,
                        unsigned* __restrict__ cnt, float* __restrict__ out) {
    __shared__ __align__(16) float s_x[32 * 68];     // 8.7 KB, stride 68
    __shared__ float s_A[32];
    __shared__ float s_m1[4][32];                    // per-wave top1/top2 (float)
    __shared__ float s_m2[4][32];
    __shared__ unsigned s_k1[4][32];                 // per-wave argmin index
    __shared__ unsigned s_idx[32];                   // final per-vec index
    __shared__ int s_fix[FIX_CAP];
    __shared__ int s_nfix;
    __shared__ float s_w[4];
    __shared__ int s_last;
    __shared__ float s_wsm[8];
    __shared__ double s_sse[SSE_SLOTS];

    const int tid = threadIdx.x;
    const int wave = tid >> 6, lane = tid & 63;
    const int vbase = blockIdx.x * 32;

    if (tid == 0) s_nfix = 0;

    // stage x (coalesced b128): 512 float4, 2 per thread
    {
        const float4* src = (const float4*)(inputs + ((size_t)vbase << 6));
#pragma unroll
        for (int i = 0; i < 2; ++i) {
            const int f = i * 256 + tid;
            float4 v = src[f];
            *(float4*)&s_x[(f >> 4) * 68 + (f & 15) * 4] = v;
        }
    }
    __syncthreads();

    // exact numpy-order ||x||^2 per vec (proven serial phase)
    if (tid < 32) s_A[tid] = np_pairwise8_sq(&s_x[tid * 68]);
    __syncthreads();

    // B-fragments (x) for all 32 vecs: per-wave, in-register (R9-proven):
    // 2 vec-tiles x 2 k-steps, hi+lo = 32 VGPRs
    short8 bhi[2][2], blo[2][2];
#pragma unroll
    for (int vt = 0; vt < 2; ++vt) {
        const int vrow = vt * 16 + (lane & 15);
#pragma unroll
        for (int step = 0; step < 2; ++step) {
            const int kb = step * 32 + (lane >> 4) * 8;
            float4 f0 = *(const float4*)&s_x[vrow * 68 + kb];
            float4 f1 = *(const float4*)&s_x[vrow * 68 + kb + 4];
            const float fs[8] = {f0.x, f0.y, f0.z, f0.w, f1.x, f1.y, f1.z, f1.w};
            short8 h, l;
#pragma unroll
            for (int j = 0; j < 8; ++j) {
                unsigned short hv = bf16_rn(fs[j]);
                float lof = fs[j] - __uint_as_float(((unsigned)hv) << 16);
                h[j] = (short)hv;
                l[j] = (short)bf16_rn(lof);
            }
            bhi[vt][step] = h;
            blo[vt][step] = l;
        }
    }

    const float INF = __builtin_inff();
    float m1[2] = {INF, INF}, m2[2] = {INF, INF};
    unsigned k1[2] = {0u, 0u};

#pragma unroll 2
    for (int tt = 0; tt < 8; ++tt) {
        const int t = wave * 8 + tt;                 // this wave's k-tiles, in order
        const int fo0 = ((t * 2 + 0) * 64 + lane) * 8;
        const int fo1 = ((t * 2 + 1) * 64 + lane) * 8;
        short8 ah0 = *(const short8*)(ahi + fo0);
        short8 ah1 = *(const short8*)(ahi + fo1);
        short8 al0 = *(const short8*)(alo + fo0);
        short8 al1 = *(const short8*)(alo + fo1);
        float4 cs = csqf[t * 64 + lane];             // = -csq/2 for 4 codewords
#pragma unroll
        for (int vt = 0; vt < 2; ++vt) {
            float4v acc = {cs.x, cs.y, cs.z, cs.w};  // csq folded into acc init
            acc = __builtin_amdgcn_mfma_f32_16x16x32_bf16(ah0, bhi[vt][0], acc, 0, 0, 0);
            acc = __builtin_amdgcn_mfma_f32_16x16x32_bf16(ah1, bhi[vt][1], acc, 0, 0, 0);
            acc = __builtin_amdgcn_mfma_f32_16x16x32_bf16(ah0, blo[vt][0], acc, 0, 0, 0);
            acc = __builtin_amdgcn_mfma_f32_16x16x32_bf16(ah1, blo[vt][1], acc, 0, 0, 0);
            acc = __builtin_amdgcn_mfma_f32_16x16x32_bf16(al0, bhi[vt][0], acc, 0, 0, 0);
            acc = __builtin_amdgcn_mfma_f32_16x16x32_bf16(al1, bhi[vt][1], acc, 0, 0, 0);
            const float Avt = s_A[vt * 16 + (lane & 15)];
#pragma unroll
            for (int r = 0; r < 4; ++r) {
                // D: col=lane&15 (=vec in tile), row=(lane>>4)*4+r (=codeword)
                float d2 = __builtin_fmaf(-2.0f, acc[r], Avt);
                const unsigned k = (unsigned)(t * 16 + (lane >> 4) * 4 + r);
                // float top-2: 5 VALU (cmp, cndmask, med3, min) vs u64's ~10
                bool lt = d2 < m1[vt];               // strict: first occurrence
                k1[vt] = lt ? k : k1[vt];
                m2[vt] = __builtin_amdgcn_fmed3f(d2, m1[vt], m2[vt]);
                m1[vt] = fminf(d2, m1[vt]);
            }
        }
    }

    // merge 4 lane-groups (disjoint k-subsets, same vec), tie-break on k
#pragma unroll
    for (int vt = 0; vt < 2; ++vt) {
#pragma unroll
        for (int off = 16; off <= 32; off <<= 1) {
            float om1 = __shfl_xor(m1[vt], off);
            float om2 = __shfl_xor(m2[vt], off);
            unsigned ok1 = __shfl_xor(k1[vt], off);
            float hi = fmaxf(m1[vt], om1);
            float lo2 = fminf(m2[vt], om2);
            bool take = (om1 < m1[vt]) || (om1 == m1[vt] && ok1 < k1[vt]);
            k1[vt] = take ? ok1 : k1[vt];
            m1[vt] = fminf(m1[vt], om1);
            m2[vt] = fminf(hi, lo2);                 // 2nd-smallest of the union
        }
        if (lane < 16) {
            s_m1[wave][vt * 16 + lane] = m1[vt];
            s_m2[wave][vt * 16 + lane] = m2[vt];
            s_k1[wave][vt * 16 + lane] = k1[vt];
        }
    }
    __syncthreads();

    // cross-wave tournament -> global top-2 per vec. Waves scan in ascending
    // k-range order; strict < keeps first occurrence; equal m1 across waves
    // collapses the gap to 0 -> replay decides exactly.
    if (tid < 32) {
        float E1 = INF, E2 = INF;
        unsigned K1 = 0u;
#pragma unroll
        for (int w = 0; w < 4; ++w) {
            float a1 = s_m1[w][tid], a2 = s_m2[w][tid];
            unsigned ak = s_k1[w][tid];
            if (a1 < E1) { E2 = fminf(E1, a2); E1 = a1; K1 = ak; }
            else         { E2 = fminf(E2, a1); }     // a2 >= a1 -> a1 suffices
        }
        s_idx[tid] = K1;
        if (__fsub_rn(E2, E1) <= EPS2) {             // ambiguous -> exact replay
            int pos = atomicAdd(&s_nfix, 1);
            if (pos < FIX_CAP) s_fix[pos] = tid;
        }
    }
    __syncthreads();

    // exact numpy-order replay for ambiguous vecs (one wave each; rare)
    {
        int nf = s_nfix; if (nf > FIX_CAP) nf = FIX_CAP;
        for (int f = wave; f < nf; f += 4) {
            const int vloc = s_fix[f];
            const float* xr = &s_x[vloc * 68];   // wave-uniform -> LDS broadcast
            const float A = s_A[vloc];
            unsigned long long best = ~0ULL;
#pragma unroll 1
            for (int r8 = 0; r8 < 8; ++r8) {
                const int k = lane * 8 + r8;
                const float* c = codebook + (k << 6);
                float p[8] = {0.f, 0.f, 0.f, 0.f, 0.f, 0.f, 0.f, 0.f};
#pragma unroll
                for (int ii = 0; ii < 64; ii += 8)
#pragma unroll
                    for (int j = 0; j < 8; ++j)
                        p[j] = __builtin_fmaf(xr[ii + j], c[ii + j], p[j]);
                float dot = __fadd_rn(__fadd_rn(__fadd_rn(p[0], p[1]), __fadd_rn(p[2], p[3])),
                                      __fadd_rn(__fadd_rn(p[4], p[5]), __fadd_rn(p[6], p[7])));
                float d2 = __fadd_rn(__fsub_rn(A, __fmul_rn(2.0f, dot)), csq[k]);
                unsigned long long e = ((unsigned long long)__float_as_uint(d2) << 32) | (unsigned)k;
                if (e < best) best = e;
            }
#pragma unroll
            for (int off = 32; off > 0; off >>= 1) {
                unsigned long long o = __shfl_down(best, off);
                if (o < best) best = o;
            }
            if (lane == 0) s_idx[vloc] = (unsigned)best;   // ties -> smallest k
        }
    }
    __syncthreads();

    // epilogue: indices + hist atomics (32/block, spread addresses)
    if (tid < 32) {
        const unsigned kf = s_idx[tid];
        out[OUT_IDX + vbase + tid] = (float)kf;
        atomicAdd(&hist[kf], 1u);
    }
    // quantized (coalesced b128) + sse
    {
        float4* dst = (float4*)(out + OUT_Q + ((size_t)vbase << 6));
        float es = 0.f;
#pragma unroll
        for (int i = 0; i < 2; ++i) {
            const int f = i * 256 + tid;
            const int row = f >> 4, col = (f & 15) * 4;
            const unsigned k = s_idx[row];
            float4 qv = *(const float4*)(codebook + ((size_t)k << 6) + col);
            dst[f] = qv;
            float4 xv = *(const float4*)&s_x[row * 68 + col];
            float d0 = qv.x - xv.x; es = __builtin_fmaf(d0, d0, es);
            float d1 = qv.y - xv.y; es = __builtin_fmaf(d1, d1, es);
            float d2 = qv.z - xv.z; es = __builtin_fmaf(d2, d2, es);
            float d3 = qv.w - xv.w; es = __builtin_fmaf(d3, d3, es);
        }
#pragma unroll
        for (int off = 32; off > 0; off >>= 1) es += __shfl_down(es, off);
        if (lane == 0) s_w[wave] = es;
    }
    __syncthreads();
    // Ticket (R2-proven tail): __syncthreads drained each wave's vmem;
    // wave-local s_waitcnt orders the sse atomic before the ticket.
    if (tid == 0) {
        atomicAdd(&sse64[blockIdx.x & (SSE_SLOTS - 1)],
                  (double)(((s_w[0] + s_w[1]) + (s_w[2] + s_w[3]))));
        asm volatile("s_waitcnt vmcnt(0)" ::: "memory");
        unsigned ticket = atomicAdd(cnt, 1u);
        s_last = (ticket == GRID_MAIN - 1) ? 1 : 0;
    }
    __syncthreads();

    // last-finishing block computes final stats (replaces vq_final launch).
    // hist/sse read via device-scope atomic-RMW. Summation order bit-identical
    // to the original vq_final: s_wsm[w]=k[64w,..), s_wsm[4+w]=k[256+64w,..).
    if (s_last) {
        float pr0 = (float)atomicAdd(&hist[tid], 0u) / 65536.0f;
        float v0 = __fmul_rn(pr0, logf(__fadd_rn(pr0, 1e-10f)));
        float pr1 = (float)atomicAdd(&hist[tid + 256], 0u) / 65536.0f;
        float v1 = __fmul_rn(pr1, logf(__fadd_rn(pr1, 1e-10f)));
#pragma unroll
        for (int off = 32; off > 0; off >>= 1) {
            v0 += __shfl_down(v0, off);
            v1 += __shfl_down(v1, off);
        }
        if (lane == 0) { s_wsm[wave] = v0; s_wsm[4 + wave] = v1; }
        if (tid < SSE_SLOTS) s_sse[tid] = atomicAdd(&sse64[tid], 0.0);
        __syncthreads();
        if (tid == 0) {
            float S = 0.f;
#pragma unroll
            for (int i = 0; i < 8; ++i) S += s_wsm[i];
            out[OUT_PERP] = expf(-S);
            double sv = 0.0;
            for (int i = 0; i < SSE_SLOTS; ++i) sv += s_sse[i];
            float m = (float)(sv / 4194304.0);            // exact /2^22
            out[OUT_LOSS] = __fadd_rn(m, __fmul_rn(0.25f, m));
        }
    }
}

extern "C" void kernel_launch(void* const* d_in, const int* in_sizes, int n_in,
                              void* d_out, int out_size, void* d_ws, size_t ws_size,
                              hipStream_t stream) {
    const float* inputs   = (const float*)d_in[0];
    const float* codebook = (const float*)d_in[1];
    float* out = (float*)d_out;
    float*          csq   = (float*)d_ws;
    double*         sse64 = (double*)((char*)d_ws + 2048);
    unsigned*       cnt   = (unsigned*)((char*)d_ws + 2304);
    unsigned*       hist  = (unsigned*)((char*)d_ws + 2560);
    unsigned short* ahi   = (unsigned short*)((char*)d_ws + 4608);
    unsigned short* alo   = (unsigned short*)((char*)d_ws + 70144);
    float4*         csqf  = (float4*)((char*)d_ws + 135680);

    vq_frag<<<18, 256, 0, stream>>>(codebook, csq, ahi, alo, csqf, hist, sse64, cnt);
    vq_main<<<GRID_MAIN, 256, 0, stream>>>(inputs, codebook, csq, ahi, alo, csqf, hist, sse64, cnt, out);
}